// Round 3
// baseline (314.181 us; speedup 1.0000x reference)
//
#include <hip/hip_runtime.h>
#include <stdint.h>

#define B_ROWS 8192
#define I_DIM  1024
#define N_DIM  1024
#define NDEG   9                  // D+1 (d = 0..8)
#define K_DIM  (I_DIM * (NDEG-1)) // 8192; k = (d-1)*1024 + i, d = 1..8 (d=0 folded into bias)

#define BM 256
#define BN 128
#define BK 64
#define NT (K_DIM / BK)           // 128 K-tiles

typedef __attribute__((ext_vector_type(8)))  short short8;
typedef __attribute__((ext_vector_type(16))) float f32x16;

__device__ __forceinline__ unsigned short f2bf(float f) {
  union { float f; uint32_t u; } v; v.f = f;
  uint32_t u = v.u;
  u += 0x7FFFu + ((u >> 16) & 1u);   // round-to-nearest-even
  return (unsigned short)(u >> 16);
}

__device__ __forceinline__ float bf2f(unsigned short h) {
  union { uint32_t u; float f; } v; v.u = ((uint32_t)h) << 16;
  return v.f;
}

// fast tanh: 1 - 2/(e^{2x}+1). v_exp-based, ~4 instrs vs libm's long path.
// x->+inf: e=inf -> 1-0 = 1; x->-inf: e=0 -> -1. Error ~1e-7 << bf16 basis quant.
__device__ __forceinline__ float fast_tanh(float x) {
  float e = __expf(2.0f * x);
  return 1.0f - __fdividef(2.0f, e + 1.0f);
}

// ---------------- fused prep: repack (blocks < repack_blocks) + basis (rest) ----------
__global__ __launch_bounds__(256) void prep_kernel(const float* __restrict__ x,
                                                   const float* __restrict__ cf,
                                                   unsigned short* __restrict__ A,
                                                   unsigned short* __restrict__ Bt,
                                                   float* __restrict__ bias,
                                                   int repack_blocks) {
  __shared__ unsigned short L[32][584];   // [i_local][o_local*9+d], padded
  const int tid = threadIdx.x;

  if ((int)blockIdx.x < repack_blocks) {
    const int bx = blockIdx.x;
    const int i0 = (bx & 31) * 32;
    const int o0 = (bx >> 5) * 64;

    #pragma unroll
    for (int j = 0; j < 18; ++j) {               // 18*256 = 4608 float4 = 32*576 floats
      const int f4  = j * 256 + tid;
      const int il  = f4 / 144;
      const int odq = f4 % 144;
      const float4 v = *reinterpret_cast<const float4*>(
          cf + ((size_t)(i0 + il) * N_DIM + o0) * NDEG + (size_t)odq * 4);
      ushort4 w;
      w.x = f2bf(v.x); w.y = f2bf(v.y); w.z = f2bf(v.z); w.w = f2bf(v.w);
      *reinterpret_cast<ushort4*>(&L[il][odq * 4]) = w;
    }
    __syncthreads();

    for (int od = tid; od < 576; od += 256) {    // od = o_local*9 + d
      const int o = od / 9, d = od % 9;
      if (d == 0) {
        float s = 0.f;
        #pragma unroll
        for (int il = 0; il < 32; ++il) s += bf2f(L[il][od]);
        atomicAdd(&bias[o0 + o], s);
      } else {
        const size_t base = (size_t)(o0 + o) * K_DIM + (size_t)(d - 1) * I_DIM + i0;
        #pragma unroll
        for (int ci = 0; ci < 4; ++ci) {         // 4 x 8 consecutive i = 64B line
          uint32_t uu[4];
          #pragma unroll
          for (int p = 0; p < 4; ++p) {
            unsigned short lo = L[ci * 8 + p * 2 + 0][od];
            unsigned short hi = L[ci * 8 + p * 2 + 1][od];
            uu[p] = (uint32_t)lo | ((uint32_t)hi << 16);
          }
          uint4 u; u.x = uu[0]; u.y = uu[1]; u.z = uu[2]; u.w = uu[3];
          *reinterpret_cast<uint4*>(Bt + base + ci * 8) = u;
        }
      }
    }
  } else {
    const int b  = blockIdx.x - repack_blocks;
    const int i0 = tid * 4;
    const float4 xv = *reinterpret_cast<const float4*>(x + (size_t)b * I_DIM + i0);
    float t[4];
    t[0] = fminf(fmaxf(fast_tanh(xv.x), -0.999f), 0.999f);
    t[1] = fminf(fmaxf(fast_tanh(xv.y), -0.999f), 0.999f);
    t[2] = fminf(fmaxf(fast_tanh(xv.z), -0.999f), 0.999f);
    t[3] = fminf(fmaxf(fast_tanh(xv.w), -0.999f), 0.999f);

    unsigned short* outb = A + (size_t)b * K_DIM + i0;
    float Tp[4] = {1.f, 1.f, 1.f, 1.f};
    float Tc[4] = {t[0], t[1], t[2], t[3]};
    #pragma unroll
    for (int d = 1; d < NDEG; ++d) {
      ushort4 o4;
      o4.x = f2bf(Tc[0]); o4.y = f2bf(Tc[1]); o4.z = f2bf(Tc[2]); o4.w = f2bf(Tc[3]);
      *reinterpret_cast<ushort4*>(outb + (size_t)(d - 1) * I_DIM) = o4;
      if (d < NDEG - 1) {
        #pragma unroll
        for (int j = 0; j < 4; ++j) {
          float Tn = 2.0f * t[j] * Tc[j] - Tp[j];
          Tp[j] = Tc[j]; Tc[j] = Tn;
        }
      }
    }
  }
}

// ---------------- GEMM: C[m,n] = bias[n] + sum_k A[m,k]*Bt[n,k] -------------------------
// 256x128 tile, BK=64, 512 threads = 8 waves (4M x 2N, 64x64 per wave).
// FRAGMENT-MAJOR LDS: block (g = 32-row group, c = 16B k-chunk) of 512 B at
// ((g*8+c)*32 + r31)*16. A wave's fragment read is then base + lane*16 ->
// sequential banks, provably conflict-free (row*128 contributes 0 to bank index,
// which is why all row-XOR swizzles failed). The permutation lives in the per-lane
// GLOBAL source of global_load_lds (LDS dest stays linear = base + lane*16).
// Triple-buffered (144 KB), one counted vmcnt(6) + one barrier per K-tile.
__global__ __launch_bounds__(512, 2) void gemm_kernel(const unsigned short* __restrict__ A,
                                                      const unsigned short* __restrict__ Bt,
                                                      const float* __restrict__ bias,
                                                      float* __restrict__ C) {
  extern __shared__ unsigned short sm[];   // A: [3][16384] @0 ; B: [3][8192] @49152 (shorts)
  const int tid  = threadIdx.x;
  const int lane = tid & 63;
  const int wave = tid >> 6;        // 0..7
  const int l31  = lane & 31;
  const int half = lane >> 5;       // 0..1 -> k-offset 8*half
  const int wm   = wave >> 1;       // 0..3
  const int wn   = wave & 1;        // 0..1
  const int m0   = blockIdx.x * BM;
  const int n0   = blockIdx.y * BN;

  const unsigned short* Abase = A  + (size_t)m0 * K_DIM;
  const unsigned short* Bbase = Bt + (size_t)n0 * K_DIM;
  const size_t rowoff = (size_t)l31 * K_DIM + half * 8;   // per-lane global row/half offset

  f32x16 acc[2][2];
  #pragma unroll
  for (int a = 0; a < 2; ++a)
    #pragma unroll
    for (int b = 0; b < 2; ++b)
      #pragma unroll
      for (int r = 0; r < 16; ++r)
        acc[a][b][r] = 0.f;

// stage-pair pa=(g,c2): lanes (l31,half) fetch A[g*32+l31][kk + c2*16 + half*8],
// land at LDS shorts [bf*16384 + pa*512 + lane*8] (= uniform base + lane*16 B).
#define STAGE_A(pa, bf, kk) {                                                               \
    const int g_ = (pa) >> 2, c2_ = (pa) & 3;                                               \
    __builtin_amdgcn_global_load_lds(                                                       \
        (const __attribute__((address_space(1))) void*)(Abase + (size_t)(g_*32)*K_DIM + rowoff + (kk) + c2_*16), \
        (__attribute__((address_space(3))) void*)&sm[(bf)*16384 + (pa)*512 + lane*8], 16, 0, 0); }
#define STAGE_B(pb, bf, kk) {                                                               \
    const int g_ = (pb) >> 2, c2_ = (pb) & 3;                                               \
    __builtin_amdgcn_global_load_lds(                                                       \
        (const __attribute__((address_space(1))) void*)(Bbase + (size_t)(g_*32)*K_DIM + rowoff + (kk) + c2_*16), \
        (__attribute__((address_space(3))) void*)&sm[49152 + (bf)*8192 + (pb)*512 + lane*8], 16, 0, 0); }
#define STAGE6(bf, kk) { STAGE_A(wave*4 + 0, bf, kk) STAGE_A(wave*4 + 1, bf, kk)            \
                         STAGE_A(wave*4 + 2, bf, kk) STAGE_A(wave*4 + 3, bf, kk)            \
                         STAGE_B(wave*2 + 0, bf, kk) STAGE_B(wave*2 + 1, bf, kk) }

  // prologue: stage tiles 0 and 1 (6 loads each); wait for tile 0 only
  STAGE6(0, 0)
  STAGE6(1, BK)
  asm volatile("s_waitcnt vmcnt(6)" ::: "memory");
  __builtin_amdgcn_s_barrier();

  int cur = 0;
  for (int kt = 0; kt < NT; ++kt) {
    const unsigned short* Asc = &sm[cur * 16384 + lane * 8];
    const unsigned short* Bsc = &sm[49152 + cur * 8192 + lane * 8];
    const int s2 = (cur == 0) ? 2 : cur - 1;     // (cur+2)%3

    // 16 fragment reads, all vaddr = lane*16 + immediate offset; conflict-free
    short8 av[2][4], bv[2][4];
    #pragma unroll
    for (int ks = 0; ks < 4; ++ks) {
      av[0][ks] = *reinterpret_cast<const short8*>(&Asc[((wm*2 + 0)*4 + ks) * 512]);
      av[1][ks] = *reinterpret_cast<const short8*>(&Asc[((wm*2 + 1)*4 + ks) * 512]);
      bv[0][ks] = *reinterpret_cast<const short8*>(&Bsc[((wn*2 + 0)*4 + ks) * 512]);
      bv[1][ks] = *reinterpret_cast<const short8*>(&Bsc[((wn*2 + 1)*4 + ks) * 512]);
    }

    // prefetch tile kt+2 into the buffer nobody touches this tile (WAR-safe: all
    // reads of buf s2 finished before the barrier at end of tile kt-1)
    if (kt + 2 < NT) { STAGE6(s2, (kt + 2) * BK) }

    // 16 MFMA, 4 independent accumulator chains
    __builtin_amdgcn_s_setprio(1);
    #pragma unroll
    for (int ks = 0; ks < 4; ++ks) {
      acc[0][0] = __builtin_amdgcn_mfma_f32_32x32x16_bf16(av[0][ks], bv[0][ks], acc[0][0], 0, 0, 0);
      acc[0][1] = __builtin_amdgcn_mfma_f32_32x32x16_bf16(av[0][ks], bv[1][ks], acc[0][1], 0, 0, 0);
      acc[1][0] = __builtin_amdgcn_mfma_f32_32x32x16_bf16(av[1][ks], bv[0][ks], acc[1][0], 0, 0, 0);
      acc[1][1] = __builtin_amdgcn_mfma_f32_32x32x16_bf16(av[1][ks], bv[1][ks], acc[1][1], 0, 0, 0);
    }
    __builtin_amdgcn_s_setprio(0);

    // single tile-boundary sync: tile kt+1's stages landed (6 newer in flight for kt+2)
    if (kt < NT - 1) {
      if (kt < NT - 2) asm volatile("s_waitcnt vmcnt(6)" ::: "memory");
      else             asm volatile("s_waitcnt vmcnt(0)" ::: "memory");
      __builtin_amdgcn_s_barrier();
    }
    cur = (cur == 2) ? 0 : cur + 1;
  }
#undef STAGE_A
#undef STAGE_B
#undef STAGE6

  // epilogue: 32x32 C/D layout col = lane&31, row = (reg&3) + 8*(reg>>2) + 4*(lane>>5)
  #pragma unroll
  for (int ni = 0; ni < 2; ++ni) {
    const int col  = n0 + wn * 64 + ni * 32 + l31;
    const float bc = bias[col];
    #pragma unroll
    for (int mi = 0; mi < 2; ++mi) {
      const int rbase = m0 + wm * 64 + mi * 32 + 4 * half;
      #pragma unroll
      for (int r = 0; r < 16; ++r) {
        const int row = rbase + (r & 3) + 8 * (r >> 2);
        C[(size_t)row * N_DIM + col] = acc[mi][ni][r] + bc;
      }
    }
  }
}

extern "C" void kernel_launch(void* const* d_in, const int* in_sizes, int n_in,
                              void* d_out, int out_size, void* d_ws, size_t ws_size,
                              hipStream_t stream) {
  const float* x      = (const float*)d_in[0];
  const float* coeffs = (const float*)d_in[1];
  float* y            = (float*)d_out;

  const size_t bt_bytes = (size_t)N_DIM * K_DIM * sizeof(unsigned short); // 16.78 MB
  unsigned short* Bt = (unsigned short*)d_ws;
  float* bias        = (float*)((char*)d_ws + bt_bytes);
  unsigned short* A  = (unsigned short*)((char*)d_ws + bt_bytes + 4096);

  // bias accumulator must start at zero (ws is poisoned 0xAA each call)
  hipMemsetAsync(bias, 0, N_DIM * sizeof(float), stream);

  // 144 KB dynamic LDS for the gemm (triple buffer)
  hipFuncSetAttribute((const void*)gemm_kernel,
                      hipFuncAttributeMaxDynamicSharedMemorySize, 147456);

  // chunk M so (Bt + bias + A-chunk) fits in workspace; full A is ~134 MB
  size_t avail    = (ws_size > bt_bytes + 4096) ? (ws_size - bt_bytes - 4096) : 0;
  size_t rows_fit = avail / ((size_t)K_DIM * sizeof(unsigned short));
  int m_chunk = (int)((rows_fit / BM) * BM);
  if (m_chunk > B_ROWS) m_chunk = B_ROWS;
  if (m_chunk < BM)     m_chunk = BM;

  for (int m0 = 0; m0 < B_ROWS; m0 += m_chunk) {
    int mc = B_ROWS - m0; if (mc > m_chunk) mc = m_chunk;
    const int rb = (m0 == 0) ? 512 : 0;   // repack blocks only in the first chunk
    prep_kernel<<<rb + mc, 256, 0, stream>>>(x + (size_t)m0 * I_DIM, coeffs, A, Bt, bias, rb);
    gemm_kernel<<<dim3(mc / BM, N_DIM / BN), 512, 147456, stream>>>(
        A, Bt, bias, y + (size_t)m0 * N_DIM);
  }
}

// Round 4
// 263.865 us; speedup vs baseline: 1.1907x; 1.1907x over previous
//
#include <hip/hip_runtime.h>
#include <stdint.h>

#define B_ROWS 8192
#define I_DIM  1024
#define N_DIM  1024
#define NDEG   9                  // D+1 (d = 0..8)
#define K_DIM  (I_DIM * (NDEG-1)) // 8192; k = (d-1)*1024 + i, d = 1..8 (d=0 folded into bias)

#define BM 256
#define BN 128
#define BK 64
#define NT (K_DIM / BK)           // 128 K-tiles

typedef __attribute__((ext_vector_type(8)))  short short8;
typedef __attribute__((ext_vector_type(16))) float f32x16;

__device__ __forceinline__ unsigned short f2bf(float f) {
  union { float f; uint32_t u; } v; v.f = f;
  uint32_t u = v.u;
  u += 0x7FFFu + ((u >> 16) & 1u);   // round-to-nearest-even
  return (unsigned short)(u >> 16);
}

__device__ __forceinline__ float bf2f(unsigned short h) {
  union { uint32_t u; float f; } v; v.u = ((uint32_t)h) << 16;
  return v.f;
}

// fast tanh: 1 - 2/(e^{2x}+1); exact limits at +-inf, err ~1e-7 << bf16 quantization
__device__ __forceinline__ float fast_tanh(float x) {
  float e = __expf(2.0f * x);
  return 1.0f - __fdividef(2.0f, e + 1.0f);
}

__device__ __forceinline__ int h2(int r) { return (r >> 2) & 7; }

// ---------------- fused prep: repack (blocks < repack_blocks) + basis (rest) ----------
// basis now 8-elem/thread: 2xfloat4 in, one 16B short8 store per degree (1KB/wave
// contiguous stores vs old 8B/lane pattern).
__global__ __launch_bounds__(256) void prep_kernel(const float* __restrict__ x,
                                                   const float* __restrict__ cf,
                                                   unsigned short* __restrict__ A,
                                                   unsigned short* __restrict__ Bt,
                                                   float* __restrict__ bias,
                                                   int repack_blocks) {
  __shared__ unsigned short L[32][584];   // [i_local][o_local*9+d], padded
  const int tid = threadIdx.x;

  if ((int)blockIdx.x < repack_blocks) {
    const int bx = blockIdx.x;
    const int i0 = (bx & 31) * 32;
    const int o0 = (bx >> 5) * 64;

    #pragma unroll
    for (int j = 0; j < 18; ++j) {               // 18*256 = 4608 float4 = 32*576 floats
      const int f4  = j * 256 + tid;
      const int il  = f4 / 144;
      const int odq = f4 % 144;
      const float4 v = *reinterpret_cast<const float4*>(
          cf + ((size_t)(i0 + il) * N_DIM + o0) * NDEG + (size_t)odq * 4);
      ushort4 w;
      w.x = f2bf(v.x); w.y = f2bf(v.y); w.z = f2bf(v.z); w.w = f2bf(v.w);
      *reinterpret_cast<ushort4*>(&L[il][odq * 4]) = w;
    }
    __syncthreads();

    for (int od = tid; od < 576; od += 256) {    // od = o_local*9 + d
      const int o = od / 9, d = od % 9;
      if (d == 0) {
        float s = 0.f;
        #pragma unroll
        for (int il = 0; il < 32; ++il) s += bf2f(L[il][od]);
        atomicAdd(&bias[o0 + o], s);
      } else {
        const size_t base = (size_t)(o0 + o) * K_DIM + (size_t)(d - 1) * I_DIM + i0;
        #pragma unroll
        for (int ci = 0; ci < 4; ++ci) {         // 4 x 8 consecutive i = 64B line
          uint32_t uu[4];
          #pragma unroll
          for (int p = 0; p < 4; ++p) {
            unsigned short lo = L[ci * 8 + p * 2 + 0][od];
            unsigned short hi = L[ci * 8 + p * 2 + 1][od];
            uu[p] = (uint32_t)lo | ((uint32_t)hi << 16);
          }
          uint4 u; u.x = uu[0]; u.y = uu[1]; u.z = uu[2]; u.w = uu[3];
          *reinterpret_cast<uint4*>(Bt + base + ci * 8) = u;
        }
      }
    }
  } else {
    // block handles 2 rows x 128 i-octets; thread = (row bit, octet j)
    const int b  = ((int)blockIdx.x - repack_blocks) * 2 + (tid >> 7);
    const int j  = tid & 127;
    const int i0 = j * 8;
    const float4 xv0 = *reinterpret_cast<const float4*>(x + (size_t)b * I_DIM + i0);
    const float4 xv1 = *reinterpret_cast<const float4*>(x + (size_t)b * I_DIM + i0 + 4);
    float t[8];
    t[0] = fast_tanh(xv0.x); t[1] = fast_tanh(xv0.y);
    t[2] = fast_tanh(xv0.z); t[3] = fast_tanh(xv0.w);
    t[4] = fast_tanh(xv1.x); t[5] = fast_tanh(xv1.y);
    t[6] = fast_tanh(xv1.z); t[7] = fast_tanh(xv1.w);
    #pragma unroll
    for (int p = 0; p < 8; ++p) t[p] = fminf(fmaxf(t[p], -0.999f), 0.999f);

    unsigned short* outb = A + (size_t)b * K_DIM + i0;
    float Tp[8], Tc[8];
    #pragma unroll
    for (int p = 0; p < 8; ++p) { Tp[p] = 1.f; Tc[p] = t[p]; }
    #pragma unroll
    for (int d = 1; d < NDEG; ++d) {
      short8 o;
      #pragma unroll
      for (int p = 0; p < 8; ++p) o[p] = (short)f2bf(Tc[p]);
      *reinterpret_cast<short8*>(outb + (size_t)(d - 1) * I_DIM) = o;
      if (d < NDEG - 1) {
        #pragma unroll
        for (int p = 0; p < 8; ++p) {
          float Tn = 2.0f * t[p] * Tc[p] - Tp[p];
          Tp[p] = Tc[p]; Tc[p] = Tn;
        }
      }
    }
  }
}

// ---------------- GEMM: C[m,n] = bias[n] + sum_k A[m,k]*Bt[n,k] -------------------------
// 256x128 tile, BK=64, 512 threads = 8 waves (4M x 2N, 64x64 per wave).
// Double-buffered row-major LDS (96 KB) with R0-style coalesced staging (source
// pre-swizzled by h2, dest linear). KEY CHANGE vs all prior rounds: ks-granular
// in-wave software pipeline — fragment reads for k-step ks+1 are issued between
// the MFMA quads of k-step ks, pinned with sched_group_barrier, so the LDS pipe
// (~1920 cy/tile) and MFMA pipe (~1033 cy/tile) overlap instead of alternating
// in bursts (the cause of the invariant ~3000 cy/tile across R0-R3).
__global__ __launch_bounds__(512, 2) void gemm_kernel(const unsigned short* __restrict__ A,
                                                      const unsigned short* __restrict__ Bt,
                                                      const float* __restrict__ bias,
                                                      float* __restrict__ C) {
  extern __shared__ unsigned short sm[];   // As: [2][16384] @0 ; Bs: [2][8192] @32768
  const int tid  = threadIdx.x;
  const int lane = tid & 63;
  const int wave = tid >> 6;        // 0..7
  const int l31  = lane & 31;
  const int half = lane >> 5;       // 0..1 -> k-offset 8*half
  const int wm   = wave >> 1;       // 0..3
  const int wn   = wave & 1;        // 0..1
  const int m0   = blockIdx.x * BM;
  const int n0   = blockIdx.y * BN;

  const int sr   = tid >> 3;        // 0..63 (staging row within issue group)
  const int slot = tid & 7;         // 16B chunk slot within 128B row

  const unsigned short* Abase = A  + (size_t)m0 * K_DIM;
  const unsigned short* Bbase = Bt + (size_t)n0 * K_DIM;

  f32x16 acc[2][2];
  #pragma unroll
  for (int a = 0; a < 2; ++a)
    #pragma unroll
    for (int b = 0; b < 2; ++b)
      #pragma unroll
      for (int r = 0; r < 16; ++r)
        acc[a][b][r] = 0.f;

#define STAGE_A(s, bf, kk) { const int r_ = (s)*64 + sr; const int gc_ = slot ^ h2(r_);     \
    __builtin_amdgcn_global_load_lds(                                                       \
        (const __attribute__((address_space(1))) void*)(Abase + (size_t)r_*K_DIM + (kk) + gc_*8), \
        (__attribute__((address_space(3))) void*)&sm[(bf)*16384 + r_*64 + slot*8], 16, 0, 0); }
#define STAGE_B(s, bf, kk) { const int r_ = (s)*64 + sr; const int gc_ = slot ^ h2(r_);     \
    __builtin_amdgcn_global_load_lds(                                                       \
        (const __attribute__((address_space(1))) void*)(Bbase + (size_t)r_*K_DIM + (kk) + gc_*8), \
        (__attribute__((address_space(3))) void*)&sm[32768 + (bf)*8192 + r_*64 + slot*8], 16, 0, 0); }
#define STAGE6(bf, kk) { STAGE_A(0, bf, kk) STAGE_A(1, bf, kk) STAGE_A(2, bf, kk) STAGE_A(3, bf, kk) \
                         STAGE_B(0, bf, kk) STAGE_B(1, bf, kk) }

  const int rowA0 = wm * 64 + l31;
  const int rowA1 = wm * 64 + 32 + l31;
  const int rowB0 = wn * 64 + l31;
  const int rowB1 = wn * 64 + 32 + l31;
  const int hA0 = h2(rowA0), hA1 = h2(rowA1), hB0 = h2(rowB0), hB1 = h2(rowB1);

  // prologue: stage tile 0 into buf 0
  STAGE6(0, 0)
  asm volatile("s_waitcnt vmcnt(0)" ::: "memory");
  __builtin_amdgcn_s_barrier();

  for (int kt = 0; kt < NT; ++kt) {
    const int  cur  = kt & 1;
    const int  nxt  = cur ^ 1;
    const bool more = (kt + 1 < NT);
    const unsigned short* Asc = &sm[cur * 16384];
    const unsigned short* Bsc = &sm[32768 + cur * 8192];

    // stage kt+1 first (full tile of latency to cover); pin at top
    if (more) { STAGE6(nxt, (kt + 1) * BK) }
    __builtin_amdgcn_sched_barrier(0);

    short8 av[2][4], bv[2][4];
#define READ4(ks) {                                                                          \
    const int c_ = (ks) * 2 + half;                                                          \
    av[0][ks] = *reinterpret_cast<const short8*>(&Asc[rowA0 * 64 + (c_ ^ hA0) * 8]);         \
    av[1][ks] = *reinterpret_cast<const short8*>(&Asc[rowA1 * 64 + (c_ ^ hA1) * 8]);         \
    bv[0][ks] = *reinterpret_cast<const short8*>(&Bsc[rowB0 * 64 + (c_ ^ hB0) * 8]);         \
    bv[1][ks] = *reinterpret_cast<const short8*>(&Bsc[rowB1 * 64 + (c_ ^ hB1) * 8]); }

    READ4(0)
    #pragma unroll
    for (int ks = 0; ks < 4; ++ks) {
      if (ks < 3) READ4(ks + 1)
      acc[0][0] = __builtin_amdgcn_mfma_f32_32x32x16_bf16(av[0][ks], bv[0][ks], acc[0][0], 0, 0, 0);
      acc[0][1] = __builtin_amdgcn_mfma_f32_32x32x16_bf16(av[0][ks], bv[1][ks], acc[0][1], 0, 0, 0);
      acc[1][0] = __builtin_amdgcn_mfma_f32_32x32x16_bf16(av[1][ks], bv[0][ks], acc[1][0], 0, 0, 0);
      acc[1][1] = __builtin_amdgcn_mfma_f32_32x32x16_bf16(av[1][ks], bv[1][ks], acc[1][1], 0, 0, 0);
      // pin the interleave: [4 ds_read][4 mfma] per ks step
      if (ks < 3) __builtin_amdgcn_sched_group_barrier(0x100, 4, 0);  // DS_READ
      __builtin_amdgcn_sched_group_barrier(0x008, 4, 0);              // MFMA
    }
#undef READ4

    // single tile-boundary sync: kt+1's 6 stages (issued at tile top) must have landed
    if (more) {
      asm volatile("s_waitcnt vmcnt(0)" ::: "memory");
      __builtin_amdgcn_s_barrier();
    }
  }
#undef STAGE_A
#undef STAGE_B
#undef STAGE6

  // epilogue: 32x32 C/D layout col = lane&31, row = (reg&3) + 8*(reg>>2) + 4*(lane>>5)
  #pragma unroll
  for (int ni = 0; ni < 2; ++ni) {
    const int col  = n0 + wn * 64 + ni * 32 + l31;
    const float bc = bias[col];
    #pragma unroll
    for (int mi = 0; mi < 2; ++mi) {
      const int rbase = m0 + wm * 64 + mi * 32 + 4 * half;
      #pragma unroll
      for (int r = 0; r < 16; ++r) {
        const int row = rbase + (r & 3) + 8 * (r >> 2);
        C[(size_t)row * N_DIM + col] = acc[mi][ni][r] + bc;
      }
    }
  }
}

extern "C" void kernel_launch(void* const* d_in, const int* in_sizes, int n_in,
                              void* d_out, int out_size, void* d_ws, size_t ws_size,
                              hipStream_t stream) {
  const float* x      = (const float*)d_in[0];
  const float* coeffs = (const float*)d_in[1];
  float* y            = (float*)d_out;

  const size_t bt_bytes = (size_t)N_DIM * K_DIM * sizeof(unsigned short); // 16.78 MB
  unsigned short* Bt = (unsigned short*)d_ws;
  float* bias        = (float*)((char*)d_ws + bt_bytes);
  unsigned short* A  = (unsigned short*)((char*)d_ws + bt_bytes + 4096);

  // bias accumulator must start at zero (ws is poisoned 0xAA each call)
  hipMemsetAsync(bias, 0, N_DIM * sizeof(float), stream);

  // 96 KB dynamic LDS for the gemm (double buffer)
  hipFuncSetAttribute((const void*)gemm_kernel,
                      hipFuncAttributeMaxDynamicSharedMemorySize, 98304);

  // chunk M so (Bt + bias + A-chunk) fits in workspace; full A is ~134 MB
  size_t avail    = (ws_size > bt_bytes + 4096) ? (ws_size - bt_bytes - 4096) : 0;
  size_t rows_fit = avail / ((size_t)K_DIM * sizeof(unsigned short));
  int m_chunk = (int)((rows_fit / BM) * BM);
  if (m_chunk > B_ROWS) m_chunk = B_ROWS;
  if (m_chunk < BM)     m_chunk = BM;

  for (int m0 = 0; m0 < B_ROWS; m0 += m_chunk) {
    int mc = B_ROWS - m0; if (mc > m_chunk) mc = m_chunk;
    const int rb = (m0 == 0) ? 512 : 0;   // repack blocks only in the first chunk
    prep_kernel<<<rb + mc / 2, 256, 0, stream>>>(x + (size_t)m0 * I_DIM, coeffs, A, Bt, bias, rb);
    gemm_kernel<<<dim3(mc / BM, N_DIM / BN), 512, 98304, stream>>>(
        A, Bt, bias, y + (size_t)m0 * N_DIM);
  }
}